// Round 5
// baseline (140.399 us; speedup 1.0000x reference)
//
#include <hip/hip_runtime.h>
#include <hip/hip_bf16.h>
#include <stdint.h>

typedef unsigned short ushort_t;
typedef __attribute__((ext_vector_type(8))) short bf16x8;   // 8 bf16 in 4 VGPRs
typedef __attribute__((ext_vector_type(4))) float f32x4;

#define BB 4
#define SS 2048
#define HDIM 1024
#define NH 16
#define DF 64
#define WWIN 16

// ---- merged QKV GEMM: C[8192,3072] = X[8192,1024] @ W[3072,1024]^T ----
#define GM 8192
#define GN 3072
#define GK 1024
#define BM 256
#define BN 256
#define BK 64
#define NT (GK / BK)            // 16 K-tiles
#define ABYTES (BM * BK * 2)    // 32768 per buffer for A
#define BUFB (ABYTES * 2)       // 65536 per buffer (A + B)
#define LDS_TOT (BUFB * 2)      // 131072

__device__ __forceinline__ ushort_t f2bf(float f) {
    uint32_t u = __float_as_uint(f);
    u = (u + 0x7FFFu + ((u >> 16) & 1u)) >> 16;   // RNE
    return (ushort_t)u;
}
__device__ __forceinline__ float bf2f(ushort_t h) {
    return __uint_as_float(((uint32_t)h) << 16);
}

__device__ __forceinline__ void gld_lds16(const void* g, void* l) {
    __builtin_amdgcn_global_load_lds(
        (const __attribute__((address_space(1))) void*)g,
        (__attribute__((address_space(3))) void*)l, 16, 0, 0);
}

// ---------------- fused fp32 -> bf16 convert (x + Wq + Wk + Wv) -----------
// region 0: x (2097152 float4), regions 1..3: weights (262144 float4 each)
__global__ void cvt_all(const float* __restrict__ x,
                        const float* __restrict__ Wq, const float* __restrict__ Wk,
                        const float* __restrict__ Wv,
                        ushort_t* __restrict__ xb, ushort_t* __restrict__ Wb) {
    const int NX = 2097152, NW = 262144;
    int i = blockIdx.x * blockDim.x + threadIdx.x;
    int st = gridDim.x * blockDim.x;
    for (; i < NX + 3 * NW; i += st) {
        const float* src; ushort_t* dst; int j;
        if (i < NX) { src = x; dst = xb; j = i; }
        else {
            int k = i - NX; int w = k >> 18; j = k & (NW - 1);
            src = (w == 0) ? Wq : ((w == 1) ? Wk : Wv);
            dst = Wb + (size_t)w * NW * 4;
        }
        float4 v = ((const float4*)src)[j];
        ushort4 o;
        o.x = f2bf(v.x); o.y = f2bf(v.y); o.z = f2bf(v.z); o.w = f2bf(v.w);
        ((ushort4*)dst)[j] = o;
    }
}

// ---------------- QKV GEMM: m201-style 8-phase schedule -------------------
// 256x256 tile, BK=64, 8 waves (2M x 4N), wave tile 128x64, phase = 64x32
// quadrant: {12 ds_read_b128 | stage 1 half-tile (2 gld_lds)} -> s_barrier ->
// setprio(1) 16 MFMA setprio(0) -> barrier. vmcnt(0) only at K-tile boundary.
// LDS chunk^(row&7) swizzle (conflict-free, R3-verified), swapped-operand MFMA.
__global__ __launch_bounds__(512, 2) void gemm_qkv8(
    const ushort_t* __restrict__ Aall,   // [8192][1024] bf16
    const ushort_t* __restrict__ Wall,   // [3072][1024] bf16 (Wq|Wk|Wv)
    const float* __restrict__ bq, const float* __restrict__ bk, const float* __restrict__ bv,
    ushort_t* __restrict__ Obase)        // [3][8192][1024] bf16
{
    extern __shared__ char lds[];
    const int t = threadIdx.x;
    const int wave = t >> 6, lane = t & 63;
    const int wm = wave >> 2, wn = wave & 3;     // 2M x 4N -> 128x64 per wave
    const int frow = lane & 15, g = lane >> 4;
    const int sw = frow & 7;

    // XCD-bijective decode: 384 blocks, 48 per XCD, bx-major within XCD
    const int bid = blockIdx.x;
    const int wgid = (bid & 7) * 48 + (bid >> 3);
    const int bx = wgid / 12;                    // 0..31 (M tile)
    const int by = wgid % 12;                    // 0..11 (N tile)
    const int m0 = bx * BM;
    const int nG0 = by * BN;

    const int rr = t >> 3, slot = t & 7;         // staging row/chunk within rounds

    // stage half-tile q (q=0,1: A rows q*128.. ; q=2,3: B rows (q-2)*128..) of K-tile kt
    auto STAGE_HALF = [&](char* Nb, int kt, int q) {
        const int kc = kt * BK;
#pragma unroll
        for (int r = 0; r < 2; ++r) {
            const int row = (q & 1) * 128 + r * 64 + rr;
            const int col = kc + ((slot ^ (rr & 7)) << 3);
            const int dst = (q & 1) * 16384 + ((r * 512 + wave * 64) << 4);
            if (q < 2)
                gld_lds16(Aall + (size_t)(m0 + row) * GK + col, Nb + dst);
            else
                gld_lds16(Wall + (size_t)(nG0 + row) * GK + col, Nb + ABYTES + dst);
        }
    };

    f32x4 acc[2][2][4][2] = {};

    // prologue: full tile 0 into buffer 0
#pragma unroll
    for (int q = 0; q < 4; ++q) STAGE_HALF(lds, 0, q);
    asm volatile("s_waitcnt vmcnt(0)\ns_barrier" ::: "memory");

#pragma unroll 1
    for (int kt = 0; kt < NT; ++kt) {
        const char* Ab = lds + (kt & 1) * BUFB;
        const char* Bb = Ab + ABYTES;
        char* Nb = lds + ((kt + 1) & 1) * BUFB;
        const bool st = (kt + 1 < NT);

#pragma unroll
        for (int q = 0; q < 4; ++q) {
            const int qm = q >> 1, qn = q & 1;

            // ds-load this quadrant's fragments (12 x b128)
            bf16x8 af[4][2], bfv[2][2];
#pragma unroll
            for (int mi = 0; mi < 4; ++mi)
#pragma unroll
                for (int kk = 0; kk < 2; ++kk)
                    af[mi][kk] = *(const bf16x8*)(Ab
                        + ((wm * 128 + qm * 64 + mi * 16 + frow) << 7)
                        + ((((kk << 2) + g) ^ sw) << 4));
#pragma unroll
            for (int nj = 0; nj < 2; ++nj)
#pragma unroll
                for (int kk = 0; kk < 2; ++kk)
                    bfv[nj][kk] = *(const bf16x8*)(Bb
                        + ((wn * 64 + qn * 32 + nj * 16 + frow) << 7)
                        + ((((kk << 2) + g) ^ sw) << 4));

            // stage one half-tile of next K-tile (loads stay in flight across phases)
            if (st) STAGE_HALF(Nb, kt + 1, q);

            asm volatile("s_barrier" ::: "memory");

            __builtin_amdgcn_s_setprio(1);
#pragma unroll
            for (int mi = 0; mi < 4; ++mi)
#pragma unroll
                for (int nj = 0; nj < 2; ++nj)
#pragma unroll
                    for (int kk = 0; kk < 2; ++kk)
                        acc[qm][qn][mi][nj] = __builtin_amdgcn_mfma_f32_16x16x32_bf16(
                            bfv[nj][kk], af[mi][kk], acc[qm][qn][mi][nj], 0, 0, 0);
            __builtin_amdgcn_s_setprio(0);

            if (q == 3 && st)
                asm volatile("s_waitcnt vmcnt(0)\ns_barrier" ::: "memory");
            else if (q != 3)
                asm volatile("s_barrier" ::: "memory");
            // kt == NT-1, q == 3: fall through to epilogue (regs only)
        }
    }

    // ---- epilogue: lane holds 4 consecutive cols at fixed row (frow) ----
#pragma unroll
    for (int qm = 0; qm < 2; ++qm)
#pragma unroll
    for (int qn = 0; qn < 2; ++qn)
#pragma unroll
    for (int nj = 0; nj < 2; ++nj) {
        const int colb = nG0 + wn * 64 + qn * 32 + nj * 16;   // 16-aligned: single z
        const int z = colb >> 10;
        const int nin = (colb & 1023) + g * 4;
        const float* bias = (z == 0) ? bq : ((z == 1) ? bk : bv);
        ushort_t* OutZ = Obase + (size_t)z * GM * 1024;
        float4 b4 = *(const float4*)(bias + nin);
#pragma unroll
        for (int mi = 0; mi < 4; ++mi) {
            const size_t rowoff = (size_t)(m0 + wm * 128 + qm * 64 + mi * 16 + frow) * 1024;
            ushort4 o;
            o.x = f2bf(acc[qm][qn][mi][nj][0] + b4.x);
            o.y = f2bf(acc[qm][qn][mi][nj][1] + b4.y);
            o.z = f2bf(acc[qm][qn][mi][nj][2] + b4.z);
            o.w = f2bf(acc[qm][qn][mi][nj][3] + b4.w);
            *(ushort4*)(OutZ + rowoff + nin) = o;
        }
    }
}

// ---------------- attention (chunked-window softmax), quad-reduce layout ----
__global__ __launch_bounds__(256) void attn_kernel(
    const ushort_t* __restrict__ Qb, const ushort_t* __restrict__ Kb, const ushort_t* __restrict__ Vb,
    const float* __restrict__ bk, const float* __restrict__ bv, float* __restrict__ out)
{
    const int wave = threadIdx.x >> 6, lane = threadIdx.x & 63;
    const int wg = blockIdx.x * 4 + wave;
    const int h = wg & 15;
    const int sb = wg >> 4;                // b*S + s
    const int s = sb & (SS - 1);
    const bool pad = (s + h < (WWIN - 1));
    const int dq = (lane & 3) << 4;

    const size_t qbase = (size_t)sb * HDIM + h * DF;
    const size_t kbase = ((size_t)sb + h - (WWIN - 1)) * HDIM;

    float p = 0.f;
    {
        const ushort_t* qp = Qb + qbase + dq;
        bf16x8 q0 = *(const bf16x8*)qp;
        bf16x8 q1 = *(const bf16x8*)(qp + 8);
        if (!pad) {
            const ushort_t* kp = Kb + kbase + ((size_t)lane << 4);
            bf16x8 k0 = *(const bf16x8*)kp;
            bf16x8 k1 = *(const bf16x8*)(kp + 8);
#pragma unroll
            for (int j = 0; j < 8; ++j) {
                p += bf2f((ushort_t)q0[j]) * bf2f((ushort_t)k0[j]);
                p += bf2f((ushort_t)q1[j]) * bf2f((ushort_t)k1[j]);
            }
        } else {
            const float* kp = bk + (lane << 4);
#pragma unroll
            for (int j = 0; j < 8; ++j) {
                p += bf2f((ushort_t)q0[j]) * kp[j];
                p += bf2f((ushort_t)q1[j]) * kp[8 + j];
            }
        }
    }
    p *= 0.125f;
    p += __shfl_xor(p, 1);
    p += __shfl_xor(p, 2);

    float m = p;
#pragma unroll
    for (int d = 4; d < 64; d <<= 1) m = fmaxf(m, __shfl_xor(m, d));
    float e = __expf(p - m);
    float sm = e;
#pragma unroll
    for (int d = 4; d < 64; d <<= 1) sm += __shfl_xor(sm, d);
    const float a = e / sm;

    float acc = 0.f;
    if (!pad) {
        const ushort_t* vrow = Vb + kbase;
#pragma unroll
        for (int ww = 0; ww < 16; ++ww) {
            float aw = __shfl(a, ww << 2);
            acc += aw * bf2f(vrow[(ww << 6) + lane]);
        }
    } else {
#pragma unroll
        for (int ww = 0; ww < 16; ++ww) {
            float aw = __shfl(a, ww << 2);
            acc += aw * bv[(ww << 6) + lane];
        }
    }
    out[qbase + lane] = acc;
}

extern "C" void kernel_launch(void* const* d_in, const int* in_sizes, int n_in,
                              void* d_out, int out_size, void* d_ws, size_t ws_size,
                              hipStream_t stream) {
    const float* x  = (const float*)d_in[0];
    const float* Wq = (const float*)d_in[1];
    const float* bq = (const float*)d_in[2];
    const float* Wk = (const float*)d_in[3];
    const float* bk = (const float*)d_in[4];
    const float* Wv = (const float*)d_in[5];
    const float* bv = (const float*)d_in[6];
    float* out = (float*)d_out;

    ushort_t* xb  = (ushort_t*)d_ws;                       // 8192*1024 bf16
    ushort_t* Wb  = xb + (size_t)8192 * 1024;              // 3 * 1024*1024 bf16
    ushort_t* QKV = Wb + (size_t)3 * 1024 * 1024;          // 3 * 8192*1024 bf16
    ushort_t* Qb  = QKV;
    ushort_t* Kb  = QKV + (size_t)8192 * 1024;
    ushort_t* Vb  = QKV + (size_t)2 * 8192 * 1024;

    cvt_all<<<2048, 256, 0, stream>>>(x, Wq, Wk, Wv, xb, Wb);

    hipFuncSetAttribute(reinterpret_cast<const void*>(gemm_qkv8),
                        hipFuncAttributeMaxDynamicSharedMemorySize, LDS_TOT);
    gemm_qkv8<<<dim3((GM / BM) * (GN / BN)), 512, LDS_TOT, stream>>>(
        xb, Wb, bq, bk, bv, QKV);

    attn_kernel<<<(BB * SS * NH) / 4, 256, 0, stream>>>(Qb, Kb, Vb, bk, bv, out);
}

// Round 6
// 123.425 us; speedup vs baseline: 1.1375x; 1.1375x over previous
//
#include <hip/hip_runtime.h>
#include <hip/hip_bf16.h>
#include <stdint.h>

typedef unsigned short ushort_t;
typedef __attribute__((ext_vector_type(8))) short bf16x8;   // 8 bf16 in 4 VGPRs
typedef __attribute__((ext_vector_type(4))) float f32x4;

#define BB 4
#define SS 2048
#define HDIM 1024
#define NH 16
#define DF 64
#define WWIN 16

// ---- merged QKV GEMM: C[8192,3072] = X[8192,1024] @ W[3072,1024]^T ----
#define GM 8192
#define GN 3072
#define GK 1024
#define BM 256
#define BN 256
#define BK 64
#define NT (GK / BK)            // 16 K-tiles
#define ABYTES 32768            // A bytes per buffer (256x64 bf16)
#define BUFB 65536              // A + B per buffer
#define LDS_TOT 131072

__device__ __forceinline__ ushort_t f2bf(float f) {
    uint32_t u = __float_as_uint(f);
    u = (u + 0x7FFFu + ((u >> 16) & 1u)) >> 16;   // RNE
    return (ushort_t)u;
}
__device__ __forceinline__ float bf2f(ushort_t h) {
    return __uint_as_float(((uint32_t)h) << 16);
}

__device__ __forceinline__ void gld_lds16(const void* g, void* l) {
    __builtin_amdgcn_global_load_lds(
        (const __attribute__((address_space(1))) void*)g,
        (__attribute__((address_space(3))) void*)l, 16, 0, 0);
}

// ---------------- fused fp32 -> bf16 convert (x + Wq + Wk + Wv) -----------
__global__ void cvt_all(const float* __restrict__ x,
                        const float* __restrict__ Wq, const float* __restrict__ Wk,
                        const float* __restrict__ Wv,
                        ushort_t* __restrict__ xb, ushort_t* __restrict__ Wb) {
    const int NX = 2097152, NW = 262144;
    int i = blockIdx.x * blockDim.x + threadIdx.x;
    int st = gridDim.x * blockDim.x;
    for (; i < NX + 3 * NW; i += st) {
        const float* src; ushort_t* dst; int j;
        if (i < NX) { src = x; dst = xb; j = i; }
        else {
            int k = i - NX; int w = k >> 18; j = k & (NW - 1);
            src = (w == 0) ? Wq : ((w == 1) ? Wk : Wv);
            dst = Wb + (size_t)w * NW * 4;
        }
        float4 v = ((const float4*)src)[j];
        ushort4 o;
        o.x = f2bf(v.x); o.y = f2bf(v.y); o.z = f2bf(v.z); o.w = f2bf(v.w);
        ((ushort4*)dst)[j] = o;
    }
}

// ---------------- QKV GEMM: counted-vmcnt 4-phase pipeline ----------------
// 256x256 tile, BK=64, 8 waves (2M x 4N), wave tile 128x64.
// LDS grouped by consumer: A = [qm-group][wm*64+sub], B = [qn-group][wn*32+sub].
// Stage cadence (tile kt+1, during kt): p0:A-g0  p1:B-g0  p2:B-g1  p3:A-g1.
// Consume lag >= 3 phases; invariant: vmcnt(4) before each barrier => all
// stages >=3 phases old have landed. No vmcnt(0) anywhere in the main loop.
// Fragment reuse: 24 ds_read_b128 per wave per K-tile (vs 48 naive).
__global__ __launch_bounds__(512, 2) void gemm_qkv8(
    const ushort_t* __restrict__ Aall,   // [8192][1024] bf16
    const ushort_t* __restrict__ Wall,   // [3072][1024] bf16 (Wq|Wk|Wv)
    const float* __restrict__ bq, const float* __restrict__ bk, const float* __restrict__ bv,
    ushort_t* __restrict__ Obase)        // [3][8192][1024] bf16
{
    extern __shared__ char lds[];
    const int t = threadIdx.x;
    const int wave = t >> 6, lane = t & 63;
    const int wm = wave >> 2, wn = wave & 3;     // 2M x 4N -> 128x64 per wave
    const int frow = lane & 15, g = lane >> 4;
    const int sw = frow & 7;
    const int rr = t >> 3, slot = t & 7;         // staging row / 16B-chunk

    // XCD-bijective decode: 384 blocks, 48 per XCD, bx-major within XCD
    const int bid = blockIdx.x;
    const int wgid = (bid & 7) * 48 + (bid >> 3);
    const int bx = wgid / 12;                    // 0..31 (M tile)
    const int by = wgid % 12;                    // 0..11 (N tile)
    const int m0 = bx * BM;
    const int nG0 = by * BN;

    // stage A group ga (rows wm*128 + ga*64 + [0,64)), round r covers wm = r
    auto STAGE_A = [&](char* Nb, int kt, int ga, int r) {
        const int grow = m0 + r * 128 + ga * 64 + rr;
        const int gcol = kt * BK + ((slot ^ (rr & 7)) << 3);
        gld_lds16(Aall + (size_t)grow * GK + gcol,
                  Nb + ga * 16384 + r * 8192 + wave * 1024);
    };
    // stage B group gb (rows wn*64 + gb*32 + [0,32)), round r covers wn = 2r,2r+1
    auto STAGE_B = [&](char* Nb, int kt, int gb, int r) {
        const int grow = nG0 + (r * 2 + (rr >> 5)) * 64 + gb * 32 + (rr & 31);
        const int gcol = kt * BK + ((slot ^ (rr & 7)) << 3);
        gld_lds16(Wall + (size_t)grow * GK + gcol,
                  Nb + ABYTES + gb * 16384 + r * 8192 + wave * 1024);
    };

    f32x4 acc[2][2][4][2] = {};
    bf16x8 afr[4][2];          // current qm-group A fragments
    bf16x8 bfr[2][2][2];       // [qn][nj][kk] - both groups held

#define LOAD_A(qm_) \
    _Pragma("unroll") \
    for (int mi = 0; mi < 4; ++mi) \
    _Pragma("unroll") \
    for (int kk = 0; kk < 2; ++kk) \
        afr[mi][kk] = *(const bf16x8*)(Ab + (qm_) * 16384 \
            + ((wm * 64 + mi * 16 + frow) << 7) \
            + ((((kk << 2) + g) ^ sw) << 4));

#define LOAD_B(qn_) \
    _Pragma("unroll") \
    for (int nj = 0; nj < 2; ++nj) \
    _Pragma("unroll") \
    for (int kk = 0; kk < 2; ++kk) \
        bfr[qn_][nj][kk] = *(const bf16x8*)(Bb + (qn_) * 16384 \
            + ((wn * 32 + nj * 16 + frow) << 7) \
            + ((((kk << 2) + g) ^ sw) << 4));

#define MFMA_Q(qm_, qn_) \
    __builtin_amdgcn_s_setprio(1); \
    _Pragma("unroll") \
    for (int mi = 0; mi < 4; ++mi) \
    _Pragma("unroll") \
    for (int nj = 0; nj < 2; ++nj) \
    _Pragma("unroll") \
    for (int kk = 0; kk < 2; ++kk) \
        acc[qm_][qn_][mi][nj] = __builtin_amdgcn_mfma_f32_16x16x32_bf16( \
            bfr[qn_][nj][kk], afr[mi][kk], acc[qm_][qn_][mi][nj], 0, 0, 0); \
    __builtin_amdgcn_s_setprio(0);

#define WAIT_BAR asm volatile("s_waitcnt vmcnt(4)\ns_barrier" ::: "memory")

    // prologue: tile 0 into buf0, consumer order (A-g0, B-g0, B-g1, A-g1)
    STAGE_A(lds, 0, 0, 0); STAGE_A(lds, 0, 0, 1);
    STAGE_B(lds, 0, 0, 0); STAGE_B(lds, 0, 0, 1);
    STAGE_B(lds, 0, 1, 0); STAGE_B(lds, 0, 1, 1);
    STAGE_A(lds, 0, 1, 0); STAGE_A(lds, 0, 1, 1);
    WAIT_BAR;   // A-g0 + B-g0 of tile 0 landed (oldest 4 of 8)

#pragma unroll 1
    for (int kt = 0; kt < NT; ++kt) {
        const char* Ab = lds + (kt & 1) * BUFB;
        const char* Bb = Ab + ABYTES;
        char* Nb = lds + ((kt + 1) & 1) * BUFB;
        const bool st = (kt + 1 < NT);

        // phase 0: read A-g0 + B-g0, stage A-g0(kt+1), MFMA (0,0)
        LOAD_A(0)
        LOAD_B(0)
        if (st) { STAGE_A(Nb, kt + 1, 0, 0); STAGE_A(Nb, kt + 1, 0, 1); }
        MFMA_Q(0, 0)
        WAIT_BAR;

        // phase 1: read B-g1, stage B-g0(kt+1), MFMA (0,1)
        LOAD_B(1)
        if (st) { STAGE_B(Nb, kt + 1, 0, 0); STAGE_B(Nb, kt + 1, 0, 1); }
        MFMA_Q(0, 1)
        WAIT_BAR;

        // phase 2: read A-g1 (overwrite afr), stage B-g1(kt+1), MFMA (1,1)
        LOAD_A(1)
        if (st) { STAGE_B(Nb, kt + 1, 1, 0); STAGE_B(Nb, kt + 1, 1, 1); }
        MFMA_Q(1, 1)
        WAIT_BAR;

        // phase 3: no reads (afr=g1, bfr[0] held since p0), stage A-g1(kt+1), MFMA (1,0)
        if (st) { STAGE_A(Nb, kt + 1, 1, 0); STAGE_A(Nb, kt + 1, 1, 1); }
        MFMA_Q(1, 0)
        if (st) WAIT_BAR;
        // last tile: fall through to register-only epilogue (no drain needed)
    }

    // ---- epilogue: lane holds 4 consecutive cols at fixed row (frow) ----
#pragma unroll
    for (int qm = 0; qm < 2; ++qm)
#pragma unroll
    for (int qn = 0; qn < 2; ++qn)
#pragma unroll
    for (int nj = 0; nj < 2; ++nj) {
        const int colb = nG0 + wn * 64 + qn * 32 + nj * 16;   // 16-aligned: single z
        const int z = colb >> 10;
        const int nin = (colb & 1023) + g * 4;
        const float* bias = (z == 0) ? bq : ((z == 1) ? bk : bv);
        ushort_t* OutZ = Obase + (size_t)z * GM * 1024;
        float4 b4 = *(const float4*)(bias + nin);
#pragma unroll
        for (int mi = 0; mi < 4; ++mi) {
            const size_t rowoff = (size_t)(m0 + wm * 128 + qm * 64 + mi * 16 + frow) * 1024;
            ushort4 o;
            o.x = f2bf(acc[qm][qn][mi][nj][0] + b4.x);
            o.y = f2bf(acc[qm][qn][mi][nj][1] + b4.y);
            o.z = f2bf(acc[qm][qn][mi][nj][2] + b4.z);
            o.w = f2bf(acc[qm][qn][mi][nj][3] + b4.w);
            *(ushort4*)(OutZ + rowoff + nin) = o;
        }
    }
#undef LOAD_A
#undef LOAD_B
#undef MFMA_Q
#undef WAIT_BAR
}

// ---------------- attention (chunked-window softmax), quad-reduce layout ----
__global__ __launch_bounds__(256) void attn_kernel(
    const ushort_t* __restrict__ Qb, const ushort_t* __restrict__ Kb, const ushort_t* __restrict__ Vb,
    const float* __restrict__ bk, const float* __restrict__ bv, float* __restrict__ out)
{
    const int wave = threadIdx.x >> 6, lane = threadIdx.x & 63;
    const int wg = blockIdx.x * 4 + wave;
    const int h = wg & 15;
    const int sb = wg >> 4;                // b*S + s
    const int s = sb & (SS - 1);
    const bool pad = (s + h < (WWIN - 1));
    const int dq = (lane & 3) << 4;

    const size_t qbase = (size_t)sb * HDIM + h * DF;
    const size_t kbase = ((size_t)sb + h - (WWIN - 1)) * HDIM;

    float p = 0.f;
    {
        const ushort_t* qp = Qb + qbase + dq;
        bf16x8 q0 = *(const bf16x8*)qp;
        bf16x8 q1 = *(const bf16x8*)(qp + 8);
        if (!pad) {
            const ushort_t* kp = Kb + kbase + ((size_t)lane << 4);
            bf16x8 k0 = *(const bf16x8*)kp;
            bf16x8 k1 = *(const bf16x8*)(kp + 8);
#pragma unroll
            for (int j = 0; j < 8; ++j) {
                p += bf2f((ushort_t)q0[j]) * bf2f((ushort_t)k0[j]);
                p += bf2f((ushort_t)q1[j]) * bf2f((ushort_t)k1[j]);
            }
        } else {
            const float* kp = bk + (lane << 4);
#pragma unroll
            for (int j = 0; j < 8; ++j) {
                p += bf2f((ushort_t)q0[j]) * kp[j];
                p += bf2f((ushort_t)q1[j]) * kp[8 + j];
            }
        }
    }
    p *= 0.125f;
    p += __shfl_xor(p, 1);
    p += __shfl_xor(p, 2);

    float m = p;
#pragma unroll
    for (int d = 4; d < 64; d <<= 1) m = fmaxf(m, __shfl_xor(m, d));
    float e = __expf(p - m);
    float sm = e;
#pragma unroll
    for (int d = 4; d < 64; d <<= 1) sm += __shfl_xor(sm, d);
    const float a = e / sm;

    float acc = 0.f;
    if (!pad) {
        const ushort_t* vrow = Vb + kbase;
#pragma unroll
        for (int ww = 0; ww < 16; ++ww) {
            float aw = __shfl(a, ww << 2);
            acc += aw * bf2f(vrow[(ww << 6) + lane]);
        }
    } else {
#pragma unroll
        for (int ww = 0; ww < 16; ++ww) {
            float aw = __shfl(a, ww << 2);
            acc += aw * bv[(ww << 6) + lane];
        }
    }
    out[qbase + lane] = acc;
}

extern "C" void kernel_launch(void* const* d_in, const int* in_sizes, int n_in,
                              void* d_out, int out_size, void* d_ws, size_t ws_size,
                              hipStream_t stream) {
    const float* x  = (const float*)d_in[0];
    const float* Wq = (const float*)d_in[1];
    const float* bq = (const float*)d_in[2];
    const float* Wk = (const float*)d_in[3];
    const float* bk = (const float*)d_in[4];
    const float* Wv = (const float*)d_in[5];
    const float* bv = (const float*)d_in[6];
    float* out = (float*)d_out;

    ushort_t* xb  = (ushort_t*)d_ws;                       // 8192*1024 bf16
    ushort_t* Wb  = xb + (size_t)8192 * 1024;              // 3 * 1024*1024 bf16
    ushort_t* QKV = Wb + (size_t)3 * 1024 * 1024;          // 3 * 8192*1024 bf16
    ushort_t* Qb  = QKV;
    ushort_t* Kb  = QKV + (size_t)8192 * 1024;
    ushort_t* Vb  = QKV + (size_t)2 * 8192 * 1024;

    cvt_all<<<2048, 256, 0, stream>>>(x, Wq, Wk, Wv, xb, Wb);

    hipFuncSetAttribute(reinterpret_cast<const void*>(gemm_qkv8),
                        hipFuncAttributeMaxDynamicSharedMemorySize, LDS_TOT);
    gemm_qkv8<<<dim3((GM / BM) * (GN / BN)), 512, LDS_TOT, stream>>>(
        xb, Wb, bq, bk, bv, QKV);

    attn_kernel<<<(BB * SS * NH) / 4, 256, 0, stream>>>(Qb, Kb, Vb, bk, bv, out);
}

// Round 7
// 113.517 us; speedup vs baseline: 1.2368x; 1.0873x over previous
//
#include <hip/hip_runtime.h>
#include <hip/hip_bf16.h>
#include <stdint.h>

typedef unsigned short ushort_t;
typedef __attribute__((ext_vector_type(8))) short bf16x8;   // 8 bf16 in 4 VGPRs
typedef __attribute__((ext_vector_type(4))) float f32x4;

#define BB 4
#define SS 2048
#define HDIM 1024
#define NH 16
#define DF 64
#define WWIN 16

// ---- merged QKV GEMM: C[8192,3072] = X[8192,1024] @ W[3072,1024]^T ----
#define GM 8192
#define GN 3072
#define GK 1024
#define BM 256
#define BN 192
#define BK 64
#define NT (GK / BK)                          // 16 K-tiles
#define ABYTES (BM * BK * 2)                  // 32768
#define LDS_TILE (BM * BK * 2 + BN * BK * 2)  // 57344 B per buffer
#define NBUF 2

__device__ __forceinline__ ushort_t f2bf(float f) {
    uint32_t u = __float_as_uint(f);
    u = (u + 0x7FFFu + ((u >> 16) & 1u)) >> 16;   // RNE
    return (ushort_t)u;
}
__device__ __forceinline__ float bf2f(ushort_t h) {
    return __uint_as_float(((uint32_t)h) << 16);
}

__device__ __forceinline__ void gld_lds16(const void* g, void* l) {
    __builtin_amdgcn_global_load_lds(
        (const __attribute__((address_space(1))) void*)g,
        (__attribute__((address_space(3))) void*)l, 16, 0, 0);
}

// ---------------- fused fp32 -> bf16 convert (x + Wq + Wk + Wv) -----------
__global__ void cvt_all(const float* __restrict__ x,
                        const float* __restrict__ Wq, const float* __restrict__ Wk,
                        const float* __restrict__ Wv,
                        ushort_t* __restrict__ xb, ushort_t* __restrict__ Wb) {
    const int NX = 2097152, NW = 262144;
    int i = blockIdx.x * blockDim.x + threadIdx.x;
    int st = gridDim.x * blockDim.x;
    for (; i < NX + 3 * NW; i += st) {
        const float* src; ushort_t* dst; int j;
        if (i < NX) { src = x; dst = xb; j = i; }
        else {
            int k = i - NX; int w = k >> 18; j = k & (NW - 1);
            src = (w == 0) ? Wq : ((w == 1) ? Wk : Wv);
            dst = Wb + (size_t)w * NW * 4;
        }
        float4 v = ((const float4*)src)[i < NX ? i : j];
        ushort4 o;
        o.x = f2bf(v.x); o.y = f2bf(v.y); o.z = f2bf(v.z); o.w = f2bf(v.w);
        ((ushort4*)dst)[i < NX ? i : j] = o;
    }
}

// ---------------- QKV GEMM: 256x192 tile, per-wave 128x48 (R4 verbatim) ----
// 8 waves (2M x 4N), BK=64, double-buffered LDS (2x56KB), issue-early staging,
// XOR-swizzled LDS chunks (chunk ^= row&7), operand-swapped MFMA epilogue,
// bijective XCD chunking (8 chunks of 8x8 tiles).
__global__ __launch_bounds__(512, 2) void gemm_qkv8(
    const ushort_t* __restrict__ Aall,   // [8192][1024] bf16
    const ushort_t* __restrict__ Wall,   // [3072][1024] bf16 (Wq|Wk|Wv)
    const float* __restrict__ bq, const float* __restrict__ bk, const float* __restrict__ bv,
    ushort_t* __restrict__ Obase)        // [3][8192][1024] bf16
{
    extern __shared__ char lds[];
    const int t = threadIdx.x;
    const int wave = t >> 6, lane = t & 63;
    const int wm = wave >> 2, wn = wave & 3;     // 2M x 4N wave grid -> 128x48 per wave
    const int frow = lane & 15, g = lane >> 4;
    const int sw = frow & 7;

    const int bid = blockIdx.x;
    const int cc = bid & 7, w = bid >> 3;
    const int bx = (cc & 3) * 8 + (w & 7);       // 0..31  (M tile)
    const int by = (cc >> 2) * 8 + (w >> 3);     // 0..15  (N tile)
    const int m0 = bx * BM;
    const int nG0 = by * BN;

    auto STAGE = [&](int bufb, int kt) {
        const int kc = kt * BK;
        char* Lb = lds + bufb;
#pragma unroll
        for (int r = 0; r < 4; ++r) {
            int idx = r * 512 + t;
            int row = idx >> 3, slot = idx & 7;
            gld_lds16(Aall + (size_t)(m0 + row) * GK + kc + ((slot ^ (row & 7)) << 3),
                      Lb + ((r * 512 + wave * 64) << 4));
        }
#pragma unroll
        for (int r = 0; r < 3; ++r) {
            int idx = r * 512 + t;
            int row = idx >> 3, slot = idx & 7;
            gld_lds16(Wall + (size_t)(nG0 + row) * GK + kc + ((slot ^ (row & 7)) << 3),
                      Lb + ABYTES + ((r * 512 + wave * 64) << 4));
        }
    };

    f32x4 acc[8][3] = {};

    STAGE(0, 0);
    asm volatile("s_waitcnt vmcnt(0)\ns_barrier" ::: "memory");

#pragma unroll 2
    for (int tt = 0; tt < NT; ++tt) {
        if (tt + 1 < NT) STAGE(((tt + 1) & 1) * LDS_TILE, tt + 1);

        const char* Ab = lds + (tt & 1) * LDS_TILE;
        const char* Bb = Ab + ABYTES;

#pragma unroll
        for (int kk = 0; kk < 2; ++kk) {
            bf16x8 af[8], bf[3];
#pragma unroll
            for (int i = 0; i < 8; ++i)
                af[i] = *(const bf16x8*)(Ab + ((wm * 128 + i * 16 + frow) << 7)
                                            + ((((kk << 2) + g) ^ sw) << 4));
#pragma unroll
            for (int j = 0; j < 3; ++j)
                bf[j] = *(const bf16x8*)(Bb + ((wn * 48 + j * 16 + frow) << 7)
                                            + ((((kk << 2) + g) ^ sw) << 4));
            __builtin_amdgcn_s_setprio(1);
#pragma unroll
            for (int i = 0; i < 8; ++i)
#pragma unroll
                for (int j = 0; j < 3; ++j)
                    acc[i][j] = __builtin_amdgcn_mfma_f32_16x16x32_bf16(bf[j], af[i], acc[i][j], 0, 0, 0);
            __builtin_amdgcn_s_setprio(0);
        }

        if (tt + 1 < NT)
            asm volatile("s_waitcnt vmcnt(0)\ns_barrier" ::: "memory");
    }

    const int m_base = m0 + wm * 128;
#pragma unroll
    for (int j = 0; j < 3; ++j) {
        const int colb = nG0 + wn * 48 + j * 16;
        const int z = colb >> 10;
        const int nin = (colb & 1023) + g * 4;
        const float* bias = (z == 0) ? bq : ((z == 1) ? bk : bv);
        ushort_t* OutZ = Obase + (size_t)z * GM * 1024;
        float4 b4 = *(const float4*)(bias + nin);
#pragma unroll
        for (int i = 0; i < 8; ++i) {
            const size_t rowoff = (size_t)(m_base + i * 16 + frow) * 1024;
            ushort4 o;
            o.x = f2bf(acc[i][j][0] + b4.x);
            o.y = f2bf(acc[i][j][1] + b4.y);
            o.z = f2bf(acc[i][j][2] + b4.z);
            o.w = f2bf(acc[i][j][3] + b4.w);
            *(ushort4*)(OutZ + rowoff + nin) = o;
        }
    }
}

// ---------------- attention: low-DS-pressure version ----------------------
// wave per (b,s,h). lane l: w = l>>2, d-slice = (l&3)*16 + [0,16).
// DS ops/wave: 2 (quad reduce) + 4 (sum) + 1 write + 4 broadcast b128 = 11
// (was 26). No max-subtraction: |score| < ~2 (sd 0.33), softmax shift-invariant.
__global__ __launch_bounds__(256) void attn_kernel(
    const ushort_t* __restrict__ Qb, const ushort_t* __restrict__ Kb, const ushort_t* __restrict__ Vb,
    const float* __restrict__ bk, const float* __restrict__ bv, float* __restrict__ out)
{
    __shared__ float aS[4][16];
    const int wave = threadIdx.x >> 6, lane = threadIdx.x & 63;
    const int wg = blockIdx.x * 4 + wave;
    const int h = wg & 15;
    const int sb = wg >> 4;                // b*S + s
    const int s = sb & (SS - 1);
    const bool pad = (s + h < (WWIN - 1));
    const int q = lane & 3;
    const int dq = q << 4;

    const size_t qbase = (size_t)sb * HDIM + h * DF;
    const size_t kbase = ((size_t)sb + h - (WWIN - 1)) * HDIM;

    // ---- QK^T partial dot (16 elems/lane) ----
    float p = 0.f;
    {
        const ushort_t* qp = Qb + qbase + dq;
        bf16x8 q0 = *(const bf16x8*)qp;
        bf16x8 q1 = *(const bf16x8*)(qp + 8);
        if (!pad) {
            const ushort_t* kp = Kb + kbase + ((size_t)lane << 4);   // contiguous 2KB/wave
            bf16x8 k0 = *(const bf16x8*)kp;
            bf16x8 k1 = *(const bf16x8*)(kp + 8);
#pragma unroll
            for (int j = 0; j < 8; ++j) {
                p += bf2f((ushort_t)q0[j]) * bf2f((ushort_t)k0[j]);
                p += bf2f((ushort_t)q1[j]) * bf2f((ushort_t)k1[j]);
            }
        } else {
            const float* kp = bk + (lane << 4);
#pragma unroll
            for (int j = 0; j < 8; ++j) {
                p += bf2f((ushort_t)q0[j]) * kp[j];
                p += bf2f((ushort_t)q1[j]) * kp[8 + j];
            }
        }
    }
    p *= 0.125f;                            // 1/sqrt(64)
    p += __shfl_xor(p, 1);
    p += __shfl_xor(p, 2);                  // lane holds score[w], replicated in quad

    // ---- softmax without max-subtraction (scores bounded, shift-invariant) ----
    float e = __expf(p);
    float sm = e;
#pragma unroll
    for (int d = 4; d < 64; d <<= 1) sm += __shfl_xor(sm, d);
    if (q == 0) aS[wave][lane >> 2] = e / sm;   // one write per w
    asm volatile("s_waitcnt lgkmcnt(0)" ::: "memory");

    // broadcast-read the 16 attention weights (same-addr b128 = conflict-free)
    const float4 a0 = *(const float4*)&aS[wave][0];
    const float4 a1 = *(const float4*)&aS[wave][4];
    const float4 a2 = *(const float4*)&aS[wave][8];
    const float4 a3 = *(const float4*)&aS[wave][12];
    const float av[16] = {a0.x, a0.y, a0.z, a0.w, a1.x, a1.y, a1.z, a1.w,
                          a2.x, a2.y, a2.z, a2.w, a3.x, a3.y, a3.z, a3.w};

    // ---- PV: out[d=lane] = sum_w a[w] * v[w*64+lane] ----
    float vv[16];
    if (!pad) {
        const ushort_t* vrow = Vb + kbase;
#pragma unroll
        for (int ww = 0; ww < 16; ++ww) vv[ww] = bf2f(vrow[(ww << 6) + lane]);
    } else {
#pragma unroll
        for (int ww = 0; ww < 16; ++ww) vv[ww] = bv[(ww << 6) + lane];
    }
    float s0 = 0.f, s1 = 0.f, s2 = 0.f, s3 = 0.f;
#pragma unroll
    for (int ww = 0; ww < 16; ww += 4) {
        s0 = fmaf(av[ww], vv[ww], s0);
        s1 = fmaf(av[ww + 1], vv[ww + 1], s1);
        s2 = fmaf(av[ww + 2], vv[ww + 2], s2);
        s3 = fmaf(av[ww + 3], vv[ww + 3], s3);
    }
    out[qbase + lane] = (s0 + s1) + (s2 + s3);
}

extern "C" void kernel_launch(void* const* d_in, const int* in_sizes, int n_in,
                              void* d_out, int out_size, void* d_ws, size_t ws_size,
                              hipStream_t stream) {
    const float* x  = (const float*)d_in[0];
    const float* Wq = (const float*)d_in[1];
    const float* bq = (const float*)d_in[2];
    const float* Wk = (const float*)d_in[3];
    const float* bk = (const float*)d_in[4];
    const float* Wv = (const float*)d_in[5];
    const float* bv = (const float*)d_in[6];
    float* out = (float*)d_out;

    ushort_t* xb  = (ushort_t*)d_ws;                       // 8192*1024 bf16
    ushort_t* Wb  = xb + (size_t)8192 * 1024;              // 3 * 1024*1024 bf16
    ushort_t* QKV = Wb + (size_t)3 * 1024 * 1024;          // 3 * 8192*1024 bf16
    ushort_t* Qb  = QKV;
    ushort_t* Kb  = QKV + (size_t)8192 * 1024;
    ushort_t* Vb  = QKV + (size_t)2 * 8192 * 1024;

    cvt_all<<<2048, 256, 0, stream>>>(x, Wq, Wk, Wv, xb, Wb);

    hipFuncSetAttribute(reinterpret_cast<const void*>(gemm_qkv8),
                        hipFuncAttributeMaxDynamicSharedMemorySize, NBUF * LDS_TILE);
    gemm_qkv8<<<dim3((GM / BM) * (GN / BN)), 512, NBUF * LDS_TILE, stream>>>(
        xb, Wb, bq, bk, bv, QKV);

    attn_kernel<<<(BB * SS * NH) / 4, 256, 0, stream>>>(Qb, Kb, Vb, bk, bv, out);
}

// Round 8
// 108.477 us; speedup vs baseline: 1.2943x; 1.0465x over previous
//
#include <hip/hip_runtime.h>
#include <hip/hip_bf16.h>
#include <stdint.h>

typedef unsigned short ushort_t;
typedef __attribute__((ext_vector_type(8))) short bf16x8;   // 8 bf16 in 4 VGPRs
typedef __attribute__((ext_vector_type(4))) float f32x4;

#define BB 4
#define SS 2048
#define HDIM 1024
#define NH 16
#define DF 64
#define WWIN 16

// ---- merged QKV GEMM: C[8192,3072] = X[8192,1024] @ W[3072,1024]^T ----
#define GM 8192
#define GN 3072
#define GK 1024
#define BM 256
#define BN 192
#define BK 64
#define NT (GK / BK)                          // 16 K-tiles
#define ABYTES (BM * BK * 2)                  // 32768
#define LDS_TILE (BM * BK * 2 + BN * BK * 2)  // 57344 B per buffer
#define NBUF 2

__device__ __forceinline__ ushort_t f2bf(float f) {
    uint32_t u = __float_as_uint(f);
    u = (u + 0x7FFFu + ((u >> 16) & 1u)) >> 16;   // RNE
    return (ushort_t)u;
}
__device__ __forceinline__ float bf2f(ushort_t h) {
    return __uint_as_float(((uint32_t)h) << 16);
}

__device__ __forceinline__ void gld_lds16(const void* g, void* l) {
    __builtin_amdgcn_global_load_lds(
        (const __attribute__((address_space(1))) void*)g,
        (__attribute__((address_space(3))) void*)l, 16, 0, 0);
}

// ---------------- fused fp32 -> bf16 convert (x + Wq + Wk + Wv) -----------
__global__ void cvt_all(const float* __restrict__ x,
                        const float* __restrict__ Wq, const float* __restrict__ Wk,
                        const float* __restrict__ Wv,
                        ushort_t* __restrict__ xb, ushort_t* __restrict__ Wb) {
    const int NX = 2097152, NW = 262144;
    int i = blockIdx.x * blockDim.x + threadIdx.x;
    int st = gridDim.x * blockDim.x;
    for (; i < NX + 3 * NW; i += st) {
        const float* src; ushort_t* dst; int j;
        if (i < NX) { src = x; dst = xb; j = i; }
        else {
            int k = i - NX; int w = k >> 18; j = k & (NW - 1);
            src = (w == 0) ? Wq : ((w == 1) ? Wk : Wv);
            dst = Wb + (size_t)w * NW * 4;
        }
        float4 v = ((const float4*)src)[j];
        ushort4 o;
        o.x = f2bf(v.x); o.y = f2bf(v.y); o.z = f2bf(v.z); o.w = f2bf(v.w);
        ((ushort4*)dst)[j] = o;
    }
}

// ---------------- QKV GEMM: 256x192 tile, per-wave 128x48 (R4 verbatim) ----
// 8 waves (2M x 4N), BK=64, double-buffered LDS (2x56KB), issue-early staging,
// XOR-swizzled LDS chunks (chunk ^= row&7), operand-swapped MFMA epilogue,
// bijective XCD chunking (8 chunks of 8x8 tiles).
__global__ __launch_bounds__(512, 2) void gemm_qkv8(
    const ushort_t* __restrict__ Aall,   // [8192][1024] bf16
    const ushort_t* __restrict__ Wall,   // [3072][1024] bf16 (Wq|Wk|Wv)
    const float* __restrict__ bq, const float* __restrict__ bk, const float* __restrict__ bv,
    ushort_t* __restrict__ Obase)        // [3][8192][1024] bf16
{
    extern __shared__ char lds[];
    const int t = threadIdx.x;
    const int wave = t >> 6, lane = t & 63;
    const int wm = wave >> 2, wn = wave & 3;     // 2M x 4N wave grid -> 128x48 per wave
    const int frow = lane & 15, g = lane >> 4;
    const int sw = frow & 7;

    const int bid = blockIdx.x;
    const int cc = bid & 7, w = bid >> 3;
    const int bx = (cc & 3) * 8 + (w & 7);       // 0..31  (M tile)
    const int by = (cc >> 2) * 8 + (w >> 3);     // 0..15  (N tile)
    const int m0 = bx * BM;
    const int nG0 = by * BN;

    auto STAGE = [&](int bufb, int kt) {
        const int kc = kt * BK;
        char* Lb = lds + bufb;
#pragma unroll
        for (int r = 0; r < 4; ++r) {
            int idx = r * 512 + t;
            int row = idx >> 3, slot = idx & 7;
            gld_lds16(Aall + (size_t)(m0 + row) * GK + kc + ((slot ^ (row & 7)) << 3),
                      Lb + ((r * 512 + wave * 64) << 4));
        }
#pragma unroll
        for (int r = 0; r < 3; ++r) {
            int idx = r * 512 + t;
            int row = idx >> 3, slot = idx & 7;
            gld_lds16(Wall + (size_t)(nG0 + row) * GK + kc + ((slot ^ (row & 7)) << 3),
                      Lb + ABYTES + ((r * 512 + wave * 64) << 4));
        }
    };

    f32x4 acc[8][3] = {};

    STAGE(0, 0);
    asm volatile("s_waitcnt vmcnt(0)\ns_barrier" ::: "memory");

#pragma unroll 2
    for (int tt = 0; tt < NT; ++tt) {
        if (tt + 1 < NT) STAGE(((tt + 1) & 1) * LDS_TILE, tt + 1);

        const char* Ab = lds + (tt & 1) * LDS_TILE;
        const char* Bb = Ab + ABYTES;

#pragma unroll
        for (int kk = 0; kk < 2; ++kk) {
            bf16x8 af[8], bf[3];
#pragma unroll
            for (int i = 0; i < 8; ++i)
                af[i] = *(const bf16x8*)(Ab + ((wm * 128 + i * 16 + frow) << 7)
                                            + ((((kk << 2) + g) ^ sw) << 4));
#pragma unroll
            for (int j = 0; j < 3; ++j)
                bf[j] = *(const bf16x8*)(Bb + ((wn * 48 + j * 16 + frow) << 7)
                                            + ((((kk << 2) + g) ^ sw) << 4));
            __builtin_amdgcn_s_setprio(1);
#pragma unroll
            for (int i = 0; i < 8; ++i)
#pragma unroll
                for (int j = 0; j < 3; ++j)
                    acc[i][j] = __builtin_amdgcn_mfma_f32_16x16x32_bf16(bf[j], af[i], acc[i][j], 0, 0, 0);
            __builtin_amdgcn_s_setprio(0);
        }

        if (tt + 1 < NT)
            asm volatile("s_waitcnt vmcnt(0)\ns_barrier" ::: "memory");
    }

    const int m_base = m0 + wm * 128;
#pragma unroll
    for (int j = 0; j < 3; ++j) {
        const int colb = nG0 + wn * 48 + j * 16;
        const int z = colb >> 10;
        const int nin = (colb & 1023) + g * 4;
        const float* bias = (z == 0) ? bq : ((z == 1) ? bk : bv);
        ushort_t* OutZ = Obase + (size_t)z * GM * 1024;
        float4 b4 = *(const float4*)(bias + nin);
#pragma unroll
        for (int i = 0; i < 8; ++i) {
            const size_t rowoff = (size_t)(m_base + i * 16 + frow) * 1024;
            ushort4 o;
            o.x = f2bf(acc[i][j][0] + b4.x);
            o.y = f2bf(acc[i][j][1] + b4.y);
            o.z = f2bf(acc[i][j][2] + b4.z);
            o.w = f2bf(acc[i][j][3] + b4.w);
            *(ushort4*)(OutZ + rowoff + nin) = o;
        }
    }
}

// ---------------- attention: XCD-localized block order ---------------------
// wave per (b,s,h). lane l: w = l>>2, d-slice = (l&3)*16 + [0,16).
// Bijective XCD remap: hw block b -> logical (b&7)*4096 + (b>>3), so each XCD
// owns a contiguous range of 1024 sequence positions; the 16x K/V row reuse
// becomes per-XCD-L2-resident instead of thrashing L3 across 8 XCDs.
__global__ __launch_bounds__(256) void attn_kernel(
    const ushort_t* __restrict__ Qb, const ushort_t* __restrict__ Kb, const ushort_t* __restrict__ Vb,
    const float* __restrict__ bk, const float* __restrict__ bv, float* __restrict__ out)
{
    __shared__ float aS[4][16];
    const int wave = threadIdx.x >> 6, lane = threadIdx.x & 63;
    const int bid = (blockIdx.x & 7) * 4096 + (blockIdx.x >> 3);   // 32768 blocks
    const int wg = bid * 4 + wave;
    const int h = wg & 15;
    const int sb = wg >> 4;                // b*S + s
    const int s = sb & (SS - 1);
    const bool pad = (s + h < (WWIN - 1));
    const int q = lane & 3;
    const int dq = q << 4;

    const size_t qbase = (size_t)sb * HDIM + h * DF;
    const size_t kbase = ((size_t)sb + h - (WWIN - 1)) * HDIM;

    // ---- QK^T partial dot (16 elems/lane) ----
    float p = 0.f;
    {
        const ushort_t* qp = Qb + qbase + dq;
        bf16x8 q0 = *(const bf16x8*)qp;
        bf16x8 q1 = *(const bf16x8*)(qp + 8);
        if (!pad) {
            const ushort_t* kp = Kb + kbase + ((size_t)lane << 4);   // contiguous 2KB/wave
            bf16x8 k0 = *(const bf16x8*)kp;
            bf16x8 k1 = *(const bf16x8*)(kp + 8);
#pragma unroll
            for (int j = 0; j < 8; ++j) {
                p += bf2f((ushort_t)q0[j]) * bf2f((ushort_t)k0[j]);
                p += bf2f((ushort_t)q1[j]) * bf2f((ushort_t)k1[j]);
            }
        } else {
            const float* kp = bk + (lane << 4);
#pragma unroll
            for (int j = 0; j < 8; ++j) {
                p += bf2f((ushort_t)q0[j]) * kp[j];
                p += bf2f((ushort_t)q1[j]) * kp[8 + j];
            }
        }
    }
    p *= 0.125f;                            // 1/sqrt(64)
    p += __shfl_xor(p, 1);
    p += __shfl_xor(p, 2);                  // lane holds score[w], replicated in quad

    // ---- softmax without max-subtraction (scores bounded, shift-invariant) ----
    float e = __expf(p);
    float sm = e;
#pragma unroll
    for (int d = 4; d < 64; d <<= 1) sm += __shfl_xor(sm, d);
    if (q == 0) aS[wave][lane >> 2] = e / sm;   // one write per w
    asm volatile("s_waitcnt lgkmcnt(0)" ::: "memory");

    // broadcast-read the 16 attention weights (same-addr b128 = conflict-free)
    const float4 a0 = *(const float4*)&aS[wave][0];
    const float4 a1 = *(const float4*)&aS[wave][4];
    const float4 a2 = *(const float4*)&aS[wave][8];
    const float4 a3 = *(const float4*)&aS[wave][12];
    const float av[16] = {a0.x, a0.y, a0.z, a0.w, a1.x, a1.y, a1.z, a1.w,
                          a2.x, a2.y, a2.z, a2.w, a3.x, a3.y, a3.z, a3.w};

    // ---- PV: out[d=lane] = sum_w a[w] * v[w*64+lane] ----
    float vv[16];
    if (!pad) {
        const ushort_t* vrow = Vb + kbase;
#pragma unroll
        for (int ww = 0; ww < 16; ++ww) vv[ww] = bf2f(vrow[(ww << 6) + lane]);
    } else {
#pragma unroll
        for (int ww = 0; ww < 16; ++ww) vv[ww] = bv[(ww << 6) + lane];
    }
    float s0 = 0.f, s1 = 0.f, s2 = 0.f, s3 = 0.f;
#pragma unroll
    for (int ww = 0; ww < 16; ww += 4) {
        s0 = fmaf(av[ww], vv[ww], s0);
        s1 = fmaf(av[ww + 1], vv[ww + 1], s1);
        s2 = fmaf(av[ww + 2], vv[ww + 2], s2);
        s3 = fmaf(av[ww + 3], vv[ww + 3], s3);
    }
    out[qbase + lane] = (s0 + s1) + (s2 + s3);
}

extern "C" void kernel_launch(void* const* d_in, const int* in_sizes, int n_in,
                              void* d_out, int out_size, void* d_ws, size_t ws_size,
                              hipStream_t stream) {
    const float* x  = (const float*)d_in[0];
    const float* Wq = (const float*)d_in[1];
    const float* bq = (const float*)d_in[2];
    const float* Wk = (const float*)d_in[3];
    const float* bk = (const float*)d_in[4];
    const float* Wv = (const float*)d_in[5];
    const float* bv = (const float*)d_in[6];
    float* out = (float*)d_out;

    ushort_t* xb  = (ushort_t*)d_ws;                       // 8192*1024 bf16
    ushort_t* Wb  = xb + (size_t)8192 * 1024;              // 3 * 1024*1024 bf16
    ushort_t* QKV = Wb + (size_t)3 * 1024 * 1024;          // 3 * 8192*1024 bf16
    ushort_t* Qb  = QKV;
    ushort_t* Kb  = QKV + (size_t)8192 * 1024;
    ushort_t* Vb  = QKV + (size_t)2 * 8192 * 1024;

    cvt_all<<<2048, 256, 0, stream>>>(x, Wq, Wk, Wv, xb, Wb);

    hipFuncSetAttribute(reinterpret_cast<const void*>(gemm_qkv8),
                        hipFuncAttributeMaxDynamicSharedMemorySize, NBUF * LDS_TILE);
    gemm_qkv8<<<dim3((GM / BM) * (GN / BN)), 512, NBUF * LDS_TILE, stream>>>(
        xb, Wb, bq, bk, bv, QKV);

    attn_kernel<<<(BB * SS * NH) / 4, 256, 0, stream>>>(Qb, Kb, Vb, bk, bv, out);
}

// Round 9
// 102.260 us; speedup vs baseline: 1.3730x; 1.0608x over previous
//
#include <hip/hip_runtime.h>
#include <hip/hip_bf16.h>
#include <stdint.h>

typedef unsigned short ushort_t;
typedef _Float16 h16x8 __attribute__((ext_vector_type(8)));   // 8 f16 in 4 VGPRs
typedef _Float16 h16x2 __attribute__((ext_vector_type(2)));
typedef __attribute__((ext_vector_type(4))) float f32x4;

#define BB 4
#define SS 2048
#define HDIM 1024
#define NH 16
#define DF 64
#define WWIN 16

// ---- merged QKV GEMM: C[8192,3072] = X[8192,1024] @ W[3072,1024]^T ----
#define GM 8192
#define GN 3072
#define GK 1024
#define BM 256
#define BN 192
#define BK 64
#define NT (GK / BK)                          // 16 K-tiles
#define ABYTES (BM * BK * 2)                  // 32768
#define LDS_TILE (BM * BK * 2 + BN * BK * 2)  // 57344 B per buffer
#define NBUF 2

#if defined(__has_builtin)
#if __has_builtin(__builtin_amdgcn_fdot2)
#define HAS_FDOT2 1
#endif
#endif

__device__ __forceinline__ ushort_t f2h(float f) {
    union { _Float16 h; ushort_t u; } c;
    c.h = (_Float16)f;                     // v_cvt_f16_f32 (RNE)
    return c.u;
}
__device__ __forceinline__ float h2f(ushort_t u) {
    union { ushort_t u; _Float16 h; } c;
    c.u = u;
    return (float)c.h;                     // v_cvt_f32_f16
}
__device__ __forceinline__ float fdot2acc(h16x2 a, h16x2 b, float c) {
#ifdef HAS_FDOT2
    return __builtin_amdgcn_fdot2(a, b, c, false);
#else
    return c + (float)a[0] * (float)b[0] + (float)a[1] * (float)b[1];
#endif
}

__device__ __forceinline__ void gld_lds16(const void* g, void* l) {
    __builtin_amdgcn_global_load_lds(
        (const __attribute__((address_space(1))) void*)g,
        (__attribute__((address_space(3))) void*)l, 16, 0, 0);
}

// ---------------- fused fp32 -> f16 convert (x + Wq + Wk + Wv) -----------
__global__ void cvt_all(const float* __restrict__ x,
                        const float* __restrict__ Wq, const float* __restrict__ Wk,
                        const float* __restrict__ Wv,
                        ushort_t* __restrict__ xb, ushort_t* __restrict__ Wb) {
    const int NX = 2097152, NW = 262144;
    int i = blockIdx.x * blockDim.x + threadIdx.x;
    int st = gridDim.x * blockDim.x;
    for (; i < NX + 3 * NW; i += st) {
        const float* src; ushort_t* dst; int j;
        if (i < NX) { src = x; dst = xb; j = i; }
        else {
            int k = i - NX; int w = k >> 18; j = k & (NW - 1);
            src = (w == 0) ? Wq : ((w == 1) ? Wk : Wv);
            dst = Wb + (size_t)w * NW * 4;
        }
        float4 v = ((const float4*)src)[j];
        ushort4 o;
        o.x = f2h(v.x); o.y = f2h(v.y); o.z = f2h(v.z); o.w = f2h(v.w);
        ((ushort4*)dst)[j] = o;
    }
}

// ---------------- QKV GEMM: 256x192 tile, per-wave 128x48 (R4 structure) ---
// f16 MFMA (same layout/rate as bf16, better mantissa). 8 waves (2M x 4N),
// BK=64, double-buffered LDS, issue-early staging, chunk^(row&7) swizzle,
// operand-swapped epilogue, bijective XCD chunking.
__global__ __launch_bounds__(512, 2) void gemm_qkv8(
    const ushort_t* __restrict__ Aall,   // [8192][1024] f16
    const ushort_t* __restrict__ Wall,   // [3072][1024] f16 (Wq|Wk|Wv)
    const float* __restrict__ bq, const float* __restrict__ bk, const float* __restrict__ bv,
    ushort_t* __restrict__ Obase)        // [3][8192][1024] f16
{
    extern __shared__ char lds[];
    const int t = threadIdx.x;
    const int wave = t >> 6, lane = t & 63;
    const int wm = wave >> 2, wn = wave & 3;     // 2M x 4N wave grid -> 128x48 per wave
    const int frow = lane & 15, g = lane >> 4;
    const int sw = frow & 7;

    const int bid = blockIdx.x;
    const int cc = bid & 7, w = bid >> 3;
    const int bx = (cc & 3) * 8 + (w & 7);       // 0..31  (M tile)
    const int by = (cc >> 2) * 8 + (w >> 3);     // 0..15  (N tile)
    const int m0 = bx * BM;
    const int nG0 = by * BN;

    auto STAGE = [&](int bufb, int kt) {
        const int kc = kt * BK;
        char* Lb = lds + bufb;
#pragma unroll
        for (int r = 0; r < 4; ++r) {
            int idx = r * 512 + t;
            int row = idx >> 3, slot = idx & 7;
            gld_lds16(Aall + (size_t)(m0 + row) * GK + kc + ((slot ^ (row & 7)) << 3),
                      Lb + ((r * 512 + wave * 64) << 4));
        }
#pragma unroll
        for (int r = 0; r < 3; ++r) {
            int idx = r * 512 + t;
            int row = idx >> 3, slot = idx & 7;
            gld_lds16(Wall + (size_t)(nG0 + row) * GK + kc + ((slot ^ (row & 7)) << 3),
                      Lb + ABYTES + ((r * 512 + wave * 64) << 4));
        }
    };

    f32x4 acc[8][3] = {};

    STAGE(0, 0);
    asm volatile("s_waitcnt vmcnt(0)\ns_barrier" ::: "memory");

#pragma unroll 2
    for (int tt = 0; tt < NT; ++tt) {
        if (tt + 1 < NT) STAGE(((tt + 1) & 1) * LDS_TILE, tt + 1);

        const char* Ab = lds + (tt & 1) * LDS_TILE;
        const char* Bb = Ab + ABYTES;

#pragma unroll
        for (int kk = 0; kk < 2; ++kk) {
            h16x8 af[8], bf[3];
#pragma unroll
            for (int i = 0; i < 8; ++i)
                af[i] = *(const h16x8*)(Ab + ((wm * 128 + i * 16 + frow) << 7)
                                           + ((((kk << 2) + g) ^ sw) << 4));
#pragma unroll
            for (int j = 0; j < 3; ++j)
                bf[j] = *(const h16x8*)(Bb + ((wn * 48 + j * 16 + frow) << 7)
                                           + ((((kk << 2) + g) ^ sw) << 4));
            __builtin_amdgcn_s_setprio(1);
#pragma unroll
            for (int i = 0; i < 8; ++i)
#pragma unroll
                for (int j = 0; j < 3; ++j)
                    acc[i][j] = __builtin_amdgcn_mfma_f32_16x16x32_f16(bf[j], af[i], acc[i][j], 0, 0, 0);
            __builtin_amdgcn_s_setprio(0);
        }

        if (tt + 1 < NT)
            asm volatile("s_waitcnt vmcnt(0)\ns_barrier" ::: "memory");
    }

    const int m_base = m0 + wm * 128;
#pragma unroll
    for (int j = 0; j < 3; ++j) {
        const int colb = nG0 + wn * 48 + j * 16;
        const int z = colb >> 10;
        const int nin = (colb & 1023) + g * 4;
        const float* bias = (z == 0) ? bq : ((z == 1) ? bk : bv);
        ushort_t* OutZ = Obase + (size_t)z * GM * 1024;
        float4 b4 = *(const float4*)(bias + nin);
#pragma unroll
        for (int i = 0; i < 8; ++i) {
            const size_t rowoff = (size_t)(m_base + i * 16 + frow) * 1024;
            ushort4 o;
            o.x = f2h(acc[i][j][0] + b4.x);
            o.y = f2h(acc[i][j][1] + b4.y);
            o.z = f2h(acc[i][j][2] + b4.z);
            o.w = f2h(acc[i][j][3] + b4.w);
            *(ushort4*)(OutZ + rowoff + nin) = o;
        }
    }
}

// ---------------- attention: f16 + fdot2, 2 queries per wave ---------------
// lane l: w = l>>2, d-slice = (l&3)*16 + [0,16). Two independent query chains
// per wave (ILP doubling). XCD-bijective remap keeps K/V reuse L2-local.
__device__ __forceinline__ float qk_dot(const ushort_t* __restrict__ Qb,
                                        const ushort_t* __restrict__ Kb,
                                        const float* __restrict__ bk,
                                        size_t qbase, size_t kbase, bool pad, int lane) {
    const int dq = (lane & 3) << 4;
    float p = 0.f;
    h16x8 q0 = *(const h16x8*)(Qb + qbase + dq);
    h16x8 q1 = *(const h16x8*)(Qb + qbase + dq + 8);
    if (!pad) {
        const ushort_t* kp = Kb + kbase + ((size_t)lane << 4);   // contiguous 2KB/wave
        h16x8 k0 = *(const h16x8*)kp;
        h16x8 k1 = *(const h16x8*)(kp + 8);
        const h16x2* qa = (const h16x2*)&q0;
        const h16x2* qb2 = (const h16x2*)&q1;
        const h16x2* ka = (const h16x2*)&k0;
        const h16x2* kb2 = (const h16x2*)&k1;
#pragma unroll
        for (int j = 0; j < 4; ++j) {
            p = fdot2acc(qa[j], ka[j], p);
            p = fdot2acc(qb2[j], kb2[j], p);
        }
    } else {
        const float* kp = bk + (lane << 4);
#pragma unroll
        for (int j = 0; j < 8; ++j) {
            p += (float)q0[j] * kp[j];
            p += (float)q1[j] * kp[8 + j];
        }
    }
    return p * 0.125f;                      // 1/sqrt(64)
}

__device__ __forceinline__ void pv_store(const ushort_t* __restrict__ Vb,
                                         const float* __restrict__ bv,
                                         float* __restrict__ out,
                                         size_t qbase, size_t kbase, bool pad,
                                         int lane, const float* av) {
    float s0 = 0.f, s1 = 0.f, s2 = 0.f, s3 = 0.f;
    if (!pad) {
        const ushort_t* vrow = Vb + kbase;
#pragma unroll
        for (int ww = 0; ww < 16; ww += 4) {
            s0 = fmaf(av[ww],     h2f(vrow[(ww << 6) + lane]),        s0);
            s1 = fmaf(av[ww + 1], h2f(vrow[((ww + 1) << 6) + lane]),  s1);
            s2 = fmaf(av[ww + 2], h2f(vrow[((ww + 2) << 6) + lane]),  s2);
            s3 = fmaf(av[ww + 3], h2f(vrow[((ww + 3) << 6) + lane]),  s3);
        }
    } else {
#pragma unroll
        for (int ww = 0; ww < 16; ww += 4) {
            s0 = fmaf(av[ww],     bv[(ww << 6) + lane],       s0);
            s1 = fmaf(av[ww + 1], bv[((ww + 1) << 6) + lane], s1);
            s2 = fmaf(av[ww + 2], bv[((ww + 2) << 6) + lane], s2);
            s3 = fmaf(av[ww + 3], bv[((ww + 3) << 6) + lane], s3);
        }
    }
    out[qbase + lane] = (s0 + s1) + (s2 + s3);
}

__global__ __launch_bounds__(256) void attn_kernel(
    const ushort_t* __restrict__ Qb, const ushort_t* __restrict__ Kb, const ushort_t* __restrict__ Vb,
    const float* __restrict__ bk, const float* __restrict__ bv, float* __restrict__ out)
{
    __shared__ float aS[4][2][16];
    const int wave = threadIdx.x >> 6, lane = threadIdx.x & 63;
    const int bid = (blockIdx.x & 7) * 2048 + (blockIdx.x >> 3);   // 16384 blocks, bijective
    const int wg0 = bid * 8 + wave * 2;
    const int wg1 = wg0 + 1;
    const int q = lane & 3;

    const int h0 = wg0 & 15, sb0 = wg0 >> 4;
    const int h1 = wg1 & 15, sb1 = wg1 >> 4;
    const bool pad0 = ((sb0 & (SS - 1)) + h0) < (WWIN - 1);
    const bool pad1 = ((sb1 & (SS - 1)) + h1) < (WWIN - 1);
    const size_t qb0 = (size_t)sb0 * HDIM + h0 * DF;
    const size_t qb1 = (size_t)sb1 * HDIM + h1 * DF;
    const size_t kb0 = pad0 ? 0 : ((size_t)sb0 + h0 - (WWIN - 1)) * HDIM;
    const size_t kb1 = pad1 ? 0 : ((size_t)sb1 + h1 - (WWIN - 1)) * HDIM;

    // ---- two independent QK chains ----
    float p0 = qk_dot(Qb, Kb, bk, qb0, kb0, pad0, lane);
    float p1 = qk_dot(Qb, Kb, bk, qb1, kb1, pad1, lane);
    p0 += __shfl_xor(p0, 1); p0 += __shfl_xor(p0, 2);
    p1 += __shfl_xor(p1, 1); p1 += __shfl_xor(p1, 2);

    // ---- softmax (no max-sub: |score| small, shift-invariant) ----
    float e0 = __expf(p0), e1 = __expf(p1);
    float sm0 = e0, sm1 = e1;
#pragma unroll
    for (int d = 4; d < 64; d <<= 1) { sm0 += __shfl_xor(sm0, d); sm1 += __shfl_xor(sm1, d); }
    if (q == 0) {
        aS[wave][0][lane >> 2] = e0 / sm0;
        aS[wave][1][lane >> 2] = e1 / sm1;
    }
    asm volatile("s_waitcnt lgkmcnt(0)" ::: "memory");

    // broadcast-read both weight vectors (same-addr b128 = conflict-free)
    float av0[16], av1[16];
#pragma unroll
    for (int r = 0; r < 4; ++r) {
        float4 a0 = *(const float4*)&aS[wave][0][r * 4];
        float4 a1 = *(const float4*)&aS[wave][1][r * 4];
        av0[r * 4] = a0.x; av0[r * 4 + 1] = a0.y; av0[r * 4 + 2] = a0.z; av0[r * 4 + 3] = a0.w;
        av1[r * 4] = a1.x; av1[r * 4 + 1] = a1.y; av1[r * 4 + 2] = a1.z; av1[r * 4 + 3] = a1.w;
    }

    // ---- PV + store, both queries ----
    pv_store(Vb, bv, out, qb0, kb0, pad0, lane, av0);
    pv_store(Vb, bv, out, qb1, kb1, pad1, lane, av1);
}

extern "C" void kernel_launch(void* const* d_in, const int* in_sizes, int n_in,
                              void* d_out, int out_size, void* d_ws, size_t ws_size,
                              hipStream_t stream) {
    const float* x  = (const float*)d_in[0];
    const float* Wq = (const float*)d_in[1];
    const float* bq = (const float*)d_in[2];
    const float* Wk = (const float*)d_in[3];
    const float* bk = (const float*)d_in[4];
    const float* Wv = (const float*)d_in[5];
    const float* bv = (const float*)d_in[6];
    float* out = (float*)d_out;

    ushort_t* xb  = (ushort_t*)d_ws;                       // 8192*1024 f16
    ushort_t* Wb  = xb + (size_t)8192 * 1024;              // 3 * 1024*1024 f16
    ushort_t* QKV = Wb + (size_t)3 * 1024 * 1024;          // 3 * 8192*1024 f16
    ushort_t* Qb  = QKV;
    ushort_t* Kb  = QKV + (size_t)8192 * 1024;
    ushort_t* Vb  = QKV + (size_t)2 * 8192 * 1024;

    cvt_all<<<2048, 256, 0, stream>>>(x, Wq, Wk, Wv, xb, Wb);

    hipFuncSetAttribute(reinterpret_cast<const void*>(gemm_qkv8),
                        hipFuncAttributeMaxDynamicSharedMemorySize, NBUF * LDS_TILE);
    gemm_qkv8<<<dim3((GM / BM) * (GN / BN)), 512, NBUF * LDS_TILE, stream>>>(
        xb, Wb, bq, bk, bv, QKV);

    attn_kernel<<<(BB * SS * NH) / 8, 256, 0, stream>>>(Qb, Kb, Vb, bk, bv, out);
}

// Round 10
// 91.224 us; speedup vs baseline: 1.5391x; 1.1210x over previous
//
#include <hip/hip_runtime.h>
#include <hip/hip_bf16.h>
#include <stdint.h>

typedef unsigned short ushort_t;
typedef _Float16 h16x8 __attribute__((ext_vector_type(8)));   // 8 f16 in 4 VGPRs
typedef _Float16 h16x2 __attribute__((ext_vector_type(2)));
typedef __attribute__((ext_vector_type(4))) float f32x4;

#define BB 4
#define SS 2048
#define HDIM 1024
#define NH 16
#define DF 64
#define WWIN 16

// ---- merged QKV GEMM: C[8192,3072] = X[8192,1024] @ W[3072,1024]^T ----
#define GM 8192
#define GN 3072
#define GK 1024
#define BM 256
#define BN 192
#define BK 64
#define NT (GK / BK)                          // 16 K-tiles
#define ABYTES (BM * BK * 2)                  // 32768
#define LDS_TILE (BM * BK * 2 + BN * BK * 2)  // 57344 B per buffer
#define NBUF 2

#if defined(__has_builtin)
#if __has_builtin(__builtin_amdgcn_fdot2)
#define HAS_FDOT2 1
#endif
#endif

__device__ __forceinline__ ushort_t f2h(float f) {
    union { _Float16 h; ushort_t u; } c;
    c.h = (_Float16)f;                     // v_cvt_f16_f32 (RNE)
    return c.u;
}
__device__ __forceinline__ float h2f(ushort_t u) {
    union { ushort_t u; _Float16 h; } c;
    c.u = u;
    return (float)c.h;                     // v_cvt_f32_f16
}
__device__ __forceinline__ float fdot2acc(h16x2 a, h16x2 b, float c) {
#ifdef HAS_FDOT2
    return __builtin_amdgcn_fdot2(a, b, c, false);
#else
    return c + (float)a[0] * (float)b[0] + (float)a[1] * (float)b[1];
#endif
}

__device__ __forceinline__ void gld_lds16(const void* g, void* l) {
    __builtin_amdgcn_global_load_lds(
        (const __attribute__((address_space(1))) void*)g,
        (__attribute__((address_space(3))) void*)l, 16, 0, 0);
}

// ------------- fused fp32 -> f16 convert (x + Wq + Wk + Wv + pad rows) -----
__global__ void cvt_all(const float* __restrict__ x,
                        const float* __restrict__ Wq, const float* __restrict__ Wk,
                        const float* __restrict__ Wv,
                        const float* __restrict__ bk, const float* __restrict__ bv,
                        ushort_t* __restrict__ xb, ushort_t* __restrict__ Wb,
                        ushort_t* __restrict__ kpadF, ushort_t* __restrict__ vpadF) {
    const int NX = 2097152, NW = 262144;
    int i = blockIdx.x * blockDim.x + threadIdx.x;
    int st = gridDim.x * blockDim.x;
    for (; i < NX + 3 * NW; i += st) {
        const float* src; ushort_t* dst; int j;
        if (i < NX) { src = x; dst = xb; j = i; }
        else {
            int k = i - NX; int w = k >> 18; j = k & (NW - 1);
            src = (w == 0) ? Wq : ((w == 1) ? Wk : Wv);
            dst = Wb + (size_t)w * NW * 4;
        }
        float4 v = ((const float4*)src)[j];
        ushort4 o;
        o.x = f2h(v.x); o.y = f2h(v.y); o.z = f2h(v.z); o.w = f2h(v.w);
        ((ushort4*)dst)[j] = o;
    }
    // pad rows: k_all/v_all for padded x rows equal the biases exactly
    if (blockIdx.x == 0) {
#pragma unroll
        for (int it = 0; it < 4; ++it) {
            int idx = it * 256 + threadIdx.x;
            if (idx < 1024) {
                kpadF[idx] = f2h(bk[idx]);
                vpadF[idx] = f2h(bv[idx]);
            }
        }
    }
}

// ---------------- QKV GEMM: 256x192 tile, per-wave 128x48 (frozen) ---------
// f16 MFMA. 8 waves (2M x 4N), BK=64, double-buffered LDS, issue-early
// staging, chunk^(row&7) swizzle, operand-swapped epilogue, XCD chunking.
__global__ __launch_bounds__(512, 2) void gemm_qkv8(
    const ushort_t* __restrict__ Aall,   // [8192][1024] f16
    const ushort_t* __restrict__ Wall,   // [3072][1024] f16 (Wq|Wk|Wv)
    const float* __restrict__ bq, const float* __restrict__ bk, const float* __restrict__ bv,
    ushort_t* __restrict__ Obase)        // [3][8192][1024] f16
{
    extern __shared__ char lds[];
    const int t = threadIdx.x;
    const int wave = t >> 6, lane = t & 63;
    const int wm = wave >> 2, wn = wave & 3;     // 2M x 4N wave grid -> 128x48 per wave
    const int frow = lane & 15, g = lane >> 4;
    const int sw = frow & 7;

    const int bid = blockIdx.x;
    const int cc = bid & 7, w = bid >> 3;
    const int bx = (cc & 3) * 8 + (w & 7);       // 0..31  (M tile)
    const int by = (cc >> 2) * 8 + (w >> 3);     // 0..15  (N tile)
    const int m0 = bx * BM;
    const int nG0 = by * BN;

    auto STAGE = [&](int bufb, int kt) {
        const int kc = kt * BK;
        char* Lb = lds + bufb;
#pragma unroll
        for (int r = 0; r < 4; ++r) {
            int idx = r * 512 + t;
            int row = idx >> 3, slot = idx & 7;
            gld_lds16(Aall + (size_t)(m0 + row) * GK + kc + ((slot ^ (row & 7)) << 3),
                      Lb + ((r * 512 + wave * 64) << 4));
        }
#pragma unroll
        for (int r = 0; r < 3; ++r) {
            int idx = r * 512 + t;
            int row = idx >> 3, slot = idx & 7;
            gld_lds16(Wall + (size_t)(nG0 + row) * GK + kc + ((slot ^ (row & 7)) << 3),
                      Lb + ABYTES + ((r * 512 + wave * 64) << 4));
        }
    };

    f32x4 acc[8][3] = {};

    STAGE(0, 0);
    asm volatile("s_waitcnt vmcnt(0)\ns_barrier" ::: "memory");

#pragma unroll 2
    for (int tt = 0; tt < NT; ++tt) {
        if (tt + 1 < NT) STAGE(((tt + 1) & 1) * LDS_TILE, tt + 1);

        const char* Ab = lds + (tt & 1) * LDS_TILE;
        const char* Bb = Ab + ABYTES;

#pragma unroll
        for (int kk = 0; kk < 2; ++kk) {
            h16x8 af[8], bf[3];
#pragma unroll
            for (int i = 0; i < 8; ++i)
                af[i] = *(const h16x8*)(Ab + ((wm * 128 + i * 16 + frow) << 7)
                                           + ((((kk << 2) + g) ^ sw) << 4));
#pragma unroll
            for (int j = 0; j < 3; ++j)
                bf[j] = *(const h16x8*)(Bb + ((wn * 48 + j * 16 + frow) << 7)
                                           + ((((kk << 2) + g) ^ sw) << 4));
            __builtin_amdgcn_s_setprio(1);
#pragma unroll
            for (int i = 0; i < 8; ++i)
#pragma unroll
                for (int j = 0; j < 3; ++j)
                    acc[i][j] = __builtin_amdgcn_mfma_f32_16x16x32_f16(bf[j], af[i], acc[i][j], 0, 0, 0);
            __builtin_amdgcn_s_setprio(0);
        }

        if (tt + 1 < NT)
            asm volatile("s_waitcnt vmcnt(0)\ns_barrier" ::: "memory");
    }

    const int m_base = m0 + wm * 128;
#pragma unroll
    for (int j = 0; j < 3; ++j) {
        const int colb = nG0 + wn * 48 + j * 16;
        const int z = colb >> 10;
        const int nin = (colb & 1023) + g * 4;
        const float* bias = (z == 0) ? bq : ((z == 1) ? bk : bv);
        ushort_t* OutZ = Obase + (size_t)z * GM * 1024;
        float4 b4 = *(const float4*)(bias + nin);
#pragma unroll
        for (int i = 0; i < 8; ++i) {
            const size_t rowoff = (size_t)(m_base + i * 16 + frow) * 1024;
            ushort4 o;
            o.x = f2h(acc[i][j][0] + b4.x);
            o.y = f2h(acc[i][j][1] + b4.y);
            o.z = f2h(acc[i][j][2] + b4.z);
            o.w = f2h(acc[i][j][3] + b4.w);
            *(ushort4*)(OutZ + rowoff + nin) = o;
        }
    }
}

// ---------------- attention: anti-diagonal r-groups -----------------------
// Block = (b, r): the 16 queries (s,h) with s+h-15 == r all read K/V row r.
// 4 waves x 4 queries; K in regs (2 ops) + V converted once per wave (16 ops,
// shared by 4 queries). Each K/V row is read by exactly ONE block ->
// single-pass HBM traffic, no cache-reuse pressure. r<0 uses f16 bias rows.
__global__ __launch_bounds__(256) void attn_kernel(
    const ushort_t* __restrict__ Qb, const ushort_t* __restrict__ Kb,
    const ushort_t* __restrict__ Vb, const ushort_t* __restrict__ kpadF,
    const ushort_t* __restrict__ vpadF, float* __restrict__ out)
{
    __shared__ float aS[4][4][16];
    const int wave = threadIdx.x >> 6, lane = threadIdx.x & 63;
    const int r = (int)blockIdx.x - (WWIN - 1);         // -15..2047
    const int bS = blockIdx.y * SS;
    const bool pad = (r < 0);
    const int rc = pad ? 0 : r;
    const ushort_t* krow = pad ? kpadF : Kb + ((size_t)(bS + rc) << 10);
    const ushort_t* vrow = pad ? vpadF : Vb + ((size_t)(bS + rc) << 10);

    // K: lane covers dims [lane*16, lane*16+16)  (w = lane>>2, dslice = lane&3)
    h16x8 k0 = *(const h16x8*)(krow + (lane << 4));
    h16x8 k1 = *(const h16x8*)(krow + (lane << 4) + 8);
    const h16x2* ka = (const h16x2*)&k0;
    const h16x2* kc = (const h16x2*)&k1;

    // V: lane = d; shared by all 4 queries of this wave
    float vv[16];
#pragma unroll
    for (int w = 0; w < 16; ++w) vv[w] = h2f(vrow[(w << 6) + lane]);

    const int dq = (lane & 3) << 4;
    bool val[4];
    size_t qb[4];

#pragma unroll
    for (int qi = 0; qi < 4; ++qi) {
        const int h = (wave << 2) + qi;
        const int s = r + (WWIN - 1) - h;
        const bool v = ((unsigned)s) < SS;
        const int sc = v ? s : 0;
        const size_t qbase = ((size_t)(bS + sc) << 10) + (h << 6);
        val[qi] = v; qb[qi] = qbase;

        h16x8 q0 = *(const h16x8*)(Qb + qbase + dq);
        h16x8 q1 = *(const h16x8*)(Qb + qbase + dq + 8);
        const h16x2* qa = (const h16x2*)&q0;
        const h16x2* qc = (const h16x2*)&q1;
        float p = 0.f;
#pragma unroll
        for (int j = 0; j < 4; ++j) {
            p = fdot2acc(qa[j], ka[j], p);
            p = fdot2acc(qc[j], kc[j], p);
        }
        p *= 0.125f;                         // 1/sqrt(64)
        p += __shfl_xor(p, 1);
        p += __shfl_xor(p, 2);               // full dot at each lane of the quad

        float e = __expf(p);                 // no max-sub: |score| small, shift-inv
        float sm = e;
#pragma unroll
        for (int d = 4; d < 64; d <<= 1) sm += __shfl_xor(sm, d);
        if ((lane & 3) == 0) aS[wave][qi][lane >> 2] = e / sm;
    }
    asm volatile("s_waitcnt lgkmcnt(0)" ::: "memory");   // wave-local: no barrier

#pragma unroll
    for (int qi = 0; qi < 4; ++qi) {
        const float4 a0 = *(const float4*)&aS[wave][qi][0];
        const float4 a1 = *(const float4*)&aS[wave][qi][4];
        const float4 a2 = *(const float4*)&aS[wave][qi][8];
        const float4 a3 = *(const float4*)&aS[wave][qi][12];
        float s0 = a0.x * vv[0] + a0.y * vv[1] + a0.z * vv[2] + a0.w * vv[3];
        float s1 = a1.x * vv[4] + a1.y * vv[5] + a1.z * vv[6] + a1.w * vv[7];
        float s2 = a2.x * vv[8] + a2.y * vv[9] + a2.z * vv[10] + a2.w * vv[11];
        float s3 = a3.x * vv[12] + a3.y * vv[13] + a3.z * vv[14] + a3.w * vv[15];
        if (val[qi]) out[qb[qi] + lane] = (s0 + s1) + (s2 + s3);
    }
}

extern "C" void kernel_launch(void* const* d_in, const int* in_sizes, int n_in,
                              void* d_out, int out_size, void* d_ws, size_t ws_size,
                              hipStream_t stream) {
    const float* x  = (const float*)d_in[0];
    const float* Wq = (const float*)d_in[1];
    const float* bq = (const float*)d_in[2];
    const float* Wk = (const float*)d_in[3];
    const float* bk = (const float*)d_in[4];
    const float* Wv = (const float*)d_in[5];
    const float* bv = (const float*)d_in[6];
    float* out = (float*)d_out;

    ushort_t* xb    = (ushort_t*)d_ws;                     // 8192*1024 f16
    ushort_t* Wb    = xb + (size_t)8192 * 1024;            // 3 * 1024*1024 f16
    ushort_t* QKV   = Wb + (size_t)3 * 1024 * 1024;        // 3 * 8192*1024 f16
    ushort_t* Qb    = QKV;
    ushort_t* Kb    = QKV + (size_t)8192 * 1024;
    ushort_t* Vb    = QKV + (size_t)2 * 8192 * 1024;
    ushort_t* kpadF = QKV + (size_t)3 * 8192 * 1024;       // 1024 f16
    ushort_t* vpadF = kpadF + 1024;                        // 1024 f16

    cvt_all<<<2048, 256, 0, stream>>>(x, Wq, Wk, Wv, bk, bv, xb, Wb, kpadF, vpadF);

    hipFuncSetAttribute(reinterpret_cast<const void*>(gemm_qkv8),
                        hipFuncAttributeMaxDynamicSharedMemorySize, NBUF * LDS_TILE);
    gemm_qkv8<<<dim3((GM / BM) * (GN / BN)), 512, NBUF * LDS_TILE, stream>>>(
        xb, Wb, bq, bk, bv, QKV);

    // blocks: x = r + 15 (r in [-15, 2047]), y = batch
    attn_kernel<<<dim3(SS + WWIN - 1, BB), 256, 0, stream>>>(
        Qb, Kb, Vb, kpadF, vpadF, out);
}